// Round 14
// baseline (688.132 us; speedup 1.0000x reference)
//
#include <hip/hip_runtime.h>
#include <math.h>

#define NB 8
#define NMEM 196608
#define NOP 65536
#define NBLK_MEM 768
#define LSEG 512
#define EPB 4096
#define NC_MEM 48   // NMEM / EPB
#define NC_OP 16    // NOP / EPB

static __device__ __forceinline__ unsigned keymap(float f) {
  unsigned u = __float_as_uint(f);
  return (u & 0x80000000u) ? ~u : (u | 0x80000000u);
}

// logsumexp state combiner: (M,T) represents M + log(T); T==0 is identity.
static __device__ __forceinline__ void comb(float& M1, float& T1, float M2, float T2) {
  if (T2 == 0.f) return;
  if (T1 == 0.f) { M1 = M2; T1 = T2; return; }
  float M = fmaxf(M1, M2);
  T1 = T1 * expf(M1 - M) + T2 * expf(M2 - M);
  M1 = M;
}

__global__ void k_zero(double* acc) {
  if (threadIdx.x < 32) acc[threadIdx.x] = 0.0;
}

// ---- radix sort: 4x8-bit passes, stable, 4096 elements/block ----
// Batch->XCD pinning: batch = blockIdx.x % 8.
__global__ void k_radix_hist0(const float* __restrict__ ml, const float* __restrict__ gm,
                              unsigned* __restrict__ hist) {
  __shared__ unsigned h[256];
  int batch = blockIdx.x % NB, cb = blockIdx.x / NB;
  int t = threadIdx.x;
  h[t] = 0;
  __syncthreads();
  const float* pm = ml + (size_t)batch * NMEM + (size_t)cb * EPB;
  const float* pg = gm + (size_t)batch * NMEM + (size_t)cb * EPB;
  #pragma unroll
  for (int r = 0; r < 16; r++) {
    unsigned key = keymap(pm[r * 256 + t] + pg[r * 256 + t]);
    atomicAdd(&h[key & 255u], 1u);
  }
  __syncthreads();
  hist[((size_t)batch * 256 + t) * NC_MEM + cb] = h[t];
}

__global__ void k_radix_hist(const unsigned long long* __restrict__ src, unsigned* __restrict__ hist,
                             int nper, int nblk, int shift) {
  __shared__ unsigned h[256];
  int batch = blockIdx.x % NB, cb = blockIdx.x / NB;
  int t = threadIdx.x;
  h[t] = 0;
  __syncthreads();
  const unsigned long long* p = src + (size_t)batch * nper + (size_t)cb * EPB;
  #pragma unroll
  for (int r = 0; r < 16; r++) {
    unsigned long long v = p[r * 256 + t];
    unsigned d = (unsigned)(v >> shift) & 255u;
    atomicAdd(&h[d], 1u);
  }
  __syncthreads();
  hist[((size_t)batch * 256 + t) * nblk + cb] = h[t];
}

// scan hist (exclusive prefix per batch) and optionally zero the other hist buffer.
__global__ void __launch_bounds__(1024) k_radix_scan(unsigned* __restrict__ hist, int L,
                                                     unsigned* __restrict__ zb) {
  int b = blockIdx.x, t = threadIdx.x;
  unsigned* h = hist + (size_t)b * L;
  int C = L / 1024;
  if (zb) {
    unsigned* z = zb + (size_t)b * L;
    for (int i = 0; i < C; i++) z[t * C + i] = 0u;
  }
  unsigned s = 0;
  for (int i = 0; i < C; i++) s += h[t * C + i];
  __shared__ unsigned ls[1024];
  ls[t] = s;
  __syncthreads();
  for (int off = 1; off < 1024; off <<= 1) {
    unsigned add = (t >= off) ? ls[t - off] : 0u;
    __syncthreads();
    ls[t] += add;
    __syncthreads();
  }
  unsigned run = (t > 0) ? ls[t - 1] : 0u;
  for (int i = 0; i < C; i++) { unsigned v = h[t * C + i]; h[t * C + i] = run; run += v; }
}

// stable in-block rank: pos = base[d] + run[d] + wave-exclusive + ballot lane rank.
#define SCATTER_BODY(GETV, WRITE)                                              \
  __shared__ unsigned base[256];                                               \
  __shared__ unsigned run[256];                                                \
  __shared__ unsigned wh[4][256];                                              \
  int t = threadIdx.x, lane = t & 63, wv = t >> 6;                             \
  base[t] = hist[((size_t)batch * 256 + t) * nblk + cb];                       \
  run[t] = 0;                                                                  \
  unsigned long long v[16];                                                    \
  GETV;                                                                        \
  __syncthreads();                                                             \
  _Pragma("unroll")                                                            \
  for (int r = 0; r < 16; r++) {                                               \
    unsigned d = (unsigned)(v[r] >> shift) & 255u;                             \
    unsigned long long m = ~0ull;                                              \
    _Pragma("unroll")                                                          \
    for (int bit = 0; bit < 8; bit++) {                                        \
      unsigned long long bal = __ballot((d >> bit) & 1u);                      \
      m &= ((d >> bit) & 1u) ? bal : ~bal;                                     \
    }                                                                          \
    unsigned rank = (unsigned)__popcll(m & ((1ull << lane) - 1ull));           \
    _Pragma("unroll")                                                          \
    for (int w = 0; w < 4; w++) wh[w][t] = 0;                                  \
    __syncthreads();                                                           \
    if (rank == 0) wh[wv][d] = (unsigned)__popcll(m);                          \
    __syncthreads();                                                           \
    {                                                                          \
      unsigned run_t = run[t];                                                 \
      _Pragma("unroll")                                                        \
      for (int w = 0; w < 4; w++) { unsigned x = wh[w][t]; wh[w][t] = run_t; run_t += x; } \
      run[t] = run_t;                                                          \
    }                                                                          \
    __syncthreads();                                                           \
    unsigned pos = base[d] + wh[wv][d] + rank;                                 \
    WRITE;                                                                     \
    __syncthreads();                                                           \
  }

// pass-0 scatter (keys built on the fly) + fused histogram for the NEXT pass
// (digit at nshift, binned by destination chunk pos>>12 — identical counts to
// a k_radix_hist over dst; integer atomics -> deterministic).
__global__ void k_radix_scatter0h(const float* __restrict__ ml, const float* __restrict__ gm,
                                  unsigned long long* __restrict__ dst, const unsigned* __restrict__ hist,
                                  unsigned* __restrict__ hist2, int nshift) {
  int batch = blockIdx.x % NB, cb = blockIdx.x / NB;
  const int nblk = NC_MEM, shift = 32;
  const float* pm = ml + (size_t)batch * NMEM + (size_t)cb * EPB;
  const float* pg = gm + (size_t)batch * NMEM + (size_t)cb * EPB;
  unsigned long long* q = dst + (size_t)batch * NMEM;
  SCATTER_BODY(
    { _Pragma("unroll")
      for (int r = 0; r < 16; r++) {
        unsigned key = keymap(pm[r * 256 + t] + pg[r * 256 + t]);
        v[r] = ((unsigned long long)key << 32) | (unsigned)(cb * EPB + r * 256 + t);
      } },
    { q[pos] = v[r];
      atomicAdd(&hist2[((size_t)batch * 256 + ((unsigned)(v[r] >> nshift) & 255u)) * nblk + (pos >> 12)], 1u); })
}

__global__ void k_radix_scatterh(const unsigned long long* __restrict__ src, unsigned long long* __restrict__ dst,
                                 const unsigned* __restrict__ hist, int nper, int nblk, int shift,
                                 unsigned* __restrict__ hist2, int nshift) {
  int batch = blockIdx.x % NB, cb = blockIdx.x / NB;
  const unsigned long long* p = src + (size_t)batch * nper + (size_t)cb * EPB;
  unsigned long long* q = dst + (size_t)batch * nper;
  SCATTER_BODY(
    { _Pragma("unroll")
      for (int r = 0; r < 16; r++) v[r] = p[r * 256 + t]; },
    { q[pos] = v[r];
      atomicAdd(&hist2[((size_t)batch * 256 + ((unsigned)(v[r] >> nshift) & 255u)) * nblk + (pos >> 12)], 1u); })
}

// last pass: write only the low 32 bits (the permutation index).
__global__ void k_radix_scatter_lo(const unsigned long long* __restrict__ src, unsigned* __restrict__ dst,
                                   const unsigned* __restrict__ hist, int nper, int nblk) {
  int batch = blockIdx.x % NB, cb = blockIdx.x / NB;
  const int shift = 56;
  const unsigned long long* p = src + (size_t)batch * nper + (size_t)cb * EPB;
  unsigned* q = dst + (size_t)batch * nper;
  SCATTER_BODY(
    { _Pragma("unroll")
      for (int r = 0; r < 16; r++) v[r] = p[r * 256 + t]; },
    { q[pos] = (unsigned)v[r]; })
}

// ---- Plackett-Luce: segmented reverse-cumlogsumexp ----
__global__ void kpl_seg(const float* __restrict__ logits, const unsigned* __restrict__ order,
                        int n, int nseg, float* __restrict__ segM, float* __restrict__ segT,
                        float* __restrict__ slog, double* __restrict__ acc, int row) {
  int b = blockIdx.x % NB;
  int sg = blockIdx.x / NB;
  int t = threadIdx.x, lane = t & 63, wv = t >> 6;
  int seg = sg * 4 + wv;
  const float* lg = logits + (size_t)b * n;
  const unsigned* od = order + (size_t)b * n + (size_t)seg * LSEG + lane * 8;
  uint4 i0 = *((const uint4*)od);
  uint4 i1 = *((const uint4*)(od + 4));
  float s0 = lg[i0.x], s1 = lg[i0.y], s2 = lg[i0.z], s3 = lg[i0.w];
  float s4 = lg[i1.x], s5 = lg[i1.y], s6 = lg[i1.z], s7 = lg[i1.w];
  float* sl = slog + (size_t)b * n + (size_t)seg * LSEG + lane * 8;
  *((float4*)sl) = make_float4(s0, s1, s2, s3);
  *((float4*)(sl + 4)) = make_float4(s4, s5, s6, s7);
  float m = fmaxf(fmaxf(fmaxf(s0, s1), fmaxf(s2, s3)),
                  fmaxf(fmaxf(s4, s5), fmaxf(s6, s7)));
  float T = expf(s0 - m) + expf(s1 - m) + expf(s2 - m) + expf(s3 - m)
          + expf(s4 - m) + expf(s5 - m) + expf(s6 - m) + expf(s7 - m);
  double ss = ((double)s0 + (double)s1) + ((double)s2 + (double)s3)
            + ((double)s4 + (double)s5) + ((double)s6 + (double)s7);
  #pragma unroll
  for (int off = 1; off < 64; off <<= 1) {
    float M2 = __shfl_xor(m, off);
    float T2 = __shfl_xor(T, off);
    comb(m, T, M2, T2);
    ss += __shfl_xor(ss, off);
  }
  __shared__ double sw[4];
  if (lane == 0) { segM[b * nseg + seg] = m; segT[b * nseg + seg] = T; sw[wv] = ss; }
  __syncthreads();
  if (t == 0) atomicAdd(&acc[row * 8 + b], (sw[0] + sw[1]) + (sw[2] + sw[3]));
}

__global__ void __launch_bounds__(512) kpl_scan(const float* __restrict__ segM, const float* __restrict__ segT,
                                                int nseg, float* __restrict__ sufM, float* __restrict__ sufT) {
  int b = blockIdx.x, t = threadIdx.x;
  __shared__ float sm[512], st_[512];
  float M = -INFINITY, T = 0.f;
  if (t < nseg) { M = segM[b * nseg + t]; T = segT[b * nseg + t]; }
  sm[t] = M; st_[t] = T;
  __syncthreads();
  for (int off = 1; off < 512; off <<= 1) {
    float M2 = -INFINITY, T2 = 0.f;
    if (t + off < 512) { M2 = sm[t + off]; T2 = st_[t + off]; }
    __syncthreads();
    comb(M, T, M2, T2);
    sm[t] = M; st_[t] = T;
    __syncthreads();
  }
  if (t < nseg) {
    float eM = -INFINITY, eT = 0.f;
    if (t + 1 < nseg) { eM = sm[t + 1]; eT = st_[t + 1]; }
    sufM[b * nseg + t] = eM; sufT[b * nseg + t] = eT;
  }
}

// Pass 3: one WAVE per segment; lane owns 8 slog elements; shfl suffix scan.
__global__ void kpl_main(const float* __restrict__ slog, int n, int nseg,
                         const float* __restrict__ sufM, const float* __restrict__ sufT,
                         double* __restrict__ acc, int row) {
  int b = blockIdx.x % NB;
  int sg = blockIdx.x / NB;
  int t = threadIdx.x, lane = t & 63, wv = t >> 6;
  int seg = sg * 4 + wv;
  const float* sl = slog + (size_t)b * n + (size_t)seg * LSEG + lane * 8;
  float4 a = *((const float4*)sl);
  float4 c = *((const float4*)(sl + 4));
  float s[8] = {a.x, a.y, a.z, a.w, c.x, c.y, c.z, c.w};
  float m = fmaxf(fmaxf(fmaxf(s[0], s[1]), fmaxf(s[2], s[3])),
                  fmaxf(fmaxf(s[4], s[5]), fmaxf(s[6], s[7])));
  float T = expf(s[0] - m) + expf(s[1] - m) + expf(s[2] - m) + expf(s[3] - m)
          + expf(s[4] - m) + expf(s[5] - m) + expf(s[6] - m) + expf(s[7] - m);
  #pragma unroll
  for (int off = 1; off < 64; off <<= 1) {
    float M2 = __shfl_down(m, off);
    float T2 = __shfl_down(T, off);
    if (lane + off < 64) comb(m, T, M2, T2);
  }
  float Mx = __shfl_down(m, 1);
  float Tx = __shfl_down(T, 1);
  if (lane == 63) { Mx = -INFINITY; Tx = 0.f; }
  comb(Mx, Tx, sufM[b * nseg + seg], sufT[b * nseg + seg]);
  float Ms[8], Ts[8];
  #pragma unroll
  for (int i = 7; i >= 0; i--) {
    float sv = s[i];
    if (Tx == 0.f) { Mx = sv; Tx = 1.f; }
    else if (sv > Mx) { Tx = Tx * expf(Mx - sv) + 1.f; Mx = sv; }
    else Tx += expf(sv - Mx);
    Ms[i] = Mx; Ts[i] = Tx;
  }
  double lsum = 0.0;
  #pragma unroll
  for (int i = 0; i < 8; i++) lsum += (double)Ms[i] + (double)logf(Ts[i]);
  #pragma unroll
  for (int off = 1; off < 64; off <<= 1) lsum += __shfl_xor(lsum, off);
  __shared__ double sw[4];
  if (lane == 0) sw[wv] = lsum;
  __syncthreads();
  if (t == 0) atomicAdd(&acc[row * 8 + b], -((sw[0] + sw[1]) + (sw[2] + sw[3])));
}

// conv1; mm block-uniform -> scalar weight loads.
__global__ void k_conv1b(const unsigned* __restrict__ permg, const float* __restrict__ pmw,
                         const float* __restrict__ pmb, float* __restrict__ mf) {
  int t = threadIdx.x;
  int b4 = blockIdx.x / NBLK_MEM;
  int g0 = (blockIdx.x % NBLK_MEM) * 256;
  int mm = g0 >> 16;
  int p = (g0 & 65535) + t;
  int i = p >> 8, j = p & 255;
  const unsigned* ad = permg + (size_t)b4 * NMEM + mm * 65536;
  float nb[3][3];
  #pragma unroll
  for (int di = 0; di < 3; di++)
    #pragma unroll
    for (int dj = 0; dj < 3; dj++) {
      int ii = i + di - 1, jj = j + dj - 1;
      nb[di][dj] = (ii >= 0 && ii < 256 && jj >= 0 && jj < 256) ? (float)ad[ii * 256 + jj] : 0.f;
    }
  unsigned c = ad[p];
  float o[8];
  #pragma unroll
  for (int oc = 0; oc < 8; oc++) {
    float s = pmb[mm * 8 + oc];
    #pragma unroll
    for (int di = 0; di < 3; di++)
      #pragma unroll
      for (int dj = 0; dj < 3; dj++)
        s += pmw[mm * 72 + oc * 9 + di * 3 + dj] * nb[di][dj];
    o[oc] = fmaxf(s, 0.f);
  }
  float4* dst = (float4*)(mf + ((size_t)b4 * NMEM + c) * 8);
  dst[0] = make_float4(o[0], o[1], o[2], o[3]);
  dst[1] = make_float4(o[4], o[5], o[6], o[7]);
}

// conv2: weights via scalar loads; pooled partials per block.
__global__ void k_conv2b(const float* __restrict__ mf, const float* __restrict__ mcw,
                         const float* __restrict__ mcb, double* __restrict__ part, int gb) {
  __shared__ float pw[4][16][4];
  int t = threadIdx.x;
  int b4 = blockIdx.x / NBLK_MEM;
  int blk = blockIdx.x % NBLK_MEM;
  int r = blk * 32 + (t >> 3);
  int l = t & 7;
  const float* base = mf + (size_t)b4 * (NMEM * 8);
  float nb[9][8];
  #pragma unroll
  for (int q = 0; q < 9; q++) {
    int rr = r + q / 3 - 1, ll = l + q % 3 - 1;
    if (rr >= 0 && rr < 24576 && ll >= 0 && ll < 8) {
      const float4* px = (const float4*)(base + ((size_t)rr * 8 + ll) * 8);
      float4 a = px[0], bb = px[1];
      nb[q][0] = a.x; nb[q][1] = a.y; nb[q][2] = a.z; nb[q][3] = a.w;
      nb[q][4] = bb.x; nb[q][5] = bb.y; nb[q][6] = bb.z; nb[q][7] = bb.w;
    } else {
      #pragma unroll
      for (int c = 0; c < 8; c++) nb[q][c] = 0.f;
    }
  }
  int lane = t & 63, wv = t >> 6;
  #pragma unroll
  for (int c2 = 0; c2 < 16; c2++) {
    float s = mcb[c2];
    #pragma unroll
    for (int c = 0; c < 8; c++)
      #pragma unroll
      for (int q = 0; q < 9; q++)
        s += mcw[c2 * 72 + c * 9 + q] * nb[q][c];
    float v = fmaxf(s, 0.f);
    v += __shfl_xor(v, 1);
    v += __shfl_xor(v, 8);
    v += __shfl_xor(v, 16);
    v += __shfl_xor(v, 32);
    if ((lane & 1) == 0 && ((t >> 3) & 7) == 0) pw[wv][c2][(lane & 7) >> 1] = v;
  }
  __syncthreads();
  if (t < 64) {
    int c2 = t >> 2, d = t & 3;
    double s = (double)pw[0][c2][d] + (double)pw[1][c2][d] + (double)pw[2][c2][d] + (double)pw[3][c2][d];
    part[((size_t)(gb + b4) * NBLK_MEM + blk) * 64 + t] = s;
  }
}

__global__ void k_pool_final(const double* __restrict__ part, double* __restrict__ pooled) {
  int b = blockIdx.x, t = threadIdx.x;
  int c2 = t >> 4, a = (t >> 2) & 3, d = t & 3;
  double s = 0.0;
  for (int j = 0; j < 192; j++)
    s += part[((size_t)b * NBLK_MEM + a * 192 + j) * 64 + c2 * 4 + d];
  pooled[b * 256 + t] = s / 12288.0;
}

__global__ void k_oplogits(const float* __restrict__ pjw, const float* __restrict__ pjb,
                           const double* __restrict__ pooled, const float* __restrict__ gop,
                           float* __restrict__ oplog, unsigned long long* __restrict__ opkv) {
  __shared__ double pl[8][256];
  int t = threadIdx.x;
  #pragma unroll
  for (int b = 0; b < 8; b++) pl[b][t] = pooled[b * 256 + t];
  __syncthreads();
  int k = blockIdx.x * 256 + t;
  const float4* row = (const float4*)(pjw + (size_t)k * 256);
  double acc[8];
  #pragma unroll
  for (int b = 0; b < 8; b++) acc[b] = 0.0;
  for (int j4 = 0; j4 < 64; j4++) {
    float4 w = row[j4];
    int j = j4 * 4;
    #pragma unroll
    for (int b = 0; b < 8; b++)
      acc[b] += (double)w.x * pl[b][j] + (double)w.y * pl[b][j + 1]
              + (double)w.z * pl[b][j + 2] + (double)w.w * pl[b][j + 3];
  }
  float bias = pjb[k];
  #pragma unroll
  for (int b = 0; b < 8; b++) {
    float ol = (float)(acc[b] + (double)bias);
    oplog[(size_t)b * NOP + k] = ol;
    float key = ol + gop[(size_t)b * NOP + k];
    opkv[(size_t)b * NOP + k] = ((unsigned long long)keymap(key) << 32) | (unsigned)k;
  }
}

static __device__ __forceinline__ float tierf(float h) {
  return h <= 2.f ? 1.f : (h <= 4.f ? 1.5f : (h <= 8.f ? 2.f : (h <= 16.f ? 3.f : 5.f)));
}
static __device__ __forceinline__ double penf(float d) {
  float fwd = d > 0.f ? d : 0.f;
  float bwd = d < 0.f ? -d : 0.f;
  return (double)(fwd * tierf(fwd)) + (double)(bwd * bwd * tierf(bwd));
}

__global__ void k_pen(const unsigned* __restrict__ perm, const unsigned* __restrict__ oo,
                      double* __restrict__ acc) {
  int b = blockIdx.x % NB;
  int k = (blockIdx.x / NB) * 256 + threadIdx.x;
  const unsigned* P = perm + (size_t)b * NMEM;
  float A = (float)P[k], Bv = (float)P[NOP + k], Cv = (float)P[2 * NOP + k];
  double pi = penf(Bv - A) + penf(Cv - Bv);
  double pe = 0.0;
  if (k < 65535) {
    unsigned k0 = oo[(size_t)b * NOP + k], k1 = oo[(size_t)b * NOP + k + 1];
    pe = penf((float)P[k1] - (float)P[2 * NOP + k0]);
  }
  __shared__ double ri[256], re[256];
  ri[threadIdx.x] = pi; re[threadIdx.x] = pe;
  __syncthreads();
  for (int off = 128; off > 0; off >>= 1) {
    if (threadIdx.x < off) { ri[threadIdx.x] += ri[threadIdx.x + off]; re[threadIdx.x] += re[threadIdx.x + off]; }
    __syncthreads();
  }
  if (threadIdx.x == 0) { atomicAdd(&acc[8 + b], ri[0]); atomicAdd(&acc[0 + b], re[0]); }
}

__global__ void k_finalize(const double* __restrict__ acc, float* __restrict__ out) {
  if (threadIdx.x < 32) out[threadIdx.x] = (float)acc[threadIdx.x];
}

extern "C" void kernel_launch(void* const* d_in, const int* in_sizes, int n_in,
                              void* d_out, int out_size, void* d_ws, size_t ws_size,
                              hipStream_t stream) {
  (void)in_sizes; (void)n_in; (void)out_size;
  const float* ml  = (const float*)d_in[0];
  const float* gm  = (const float*)d_in[1];
  const float* gop = (const float*)d_in[2];
  const float* pmw = (const float*)d_in[3];
  const float* pmb = (const float*)d_in[4];
  const float* mcw = (const float*)d_in[5];
  const float* mcb = (const float*)d_in[6];
  const float* pjw = (const float*)d_in[7];
  const float* pjb = (const float*)d_in[8];
  float* out = (float*)d_out;
  char* ws = (char*)d_ws;

  unsigned long long* kvA = (unsigned long long*)(ws + 0);          // 12,582,912
  unsigned long long* kvB = (unsigned long long*)(ws + 12582912);   // 12,582,912
  unsigned* histA  = (unsigned*)(ws + 25165824);                    //   393,216
  unsigned* histB  = (unsigned*)(ws + 25559040);                    //   393,216
  unsigned* perm   = (unsigned*)(ws + 31457280);                    //  6,291,456
  double*   part   = (double*)(ws + 37748736);                      //  3,145,728
  double*   pooled = (double*)(ws + 40894464);
  double*   acc    = (double*)(ws + 40910848);
  float*    segM   = (float*)(ws + 40911104);
  float*    segT   = (float*)(ws + 40923392);
  float*    sufM   = (float*)(ws + 40935680);
  float*    sufT   = (float*)(ws + 40947968);
  float*    slog  = (float*)(ws + 12582912);                        // reuses dead kvB
  float* mfsmall = (float*)(ws + 0);                                // fallback conv region
  float* mfbig   = (float*)(ws + 67108864);                         // 8-batch conv region (50.3MB)
  unsigned long long* opkvA = (unsigned long long*)(ws + 0);
  unsigned long long* opkvB = (unsigned long long*)(ws + 4194304);
  float*    oplog = (float*)(ws + 8388608);
  unsigned* oo    = (unsigned*)(ws + 10485760);
  const size_t need_big = 67108864ull + (size_t)NB * NMEM * 8 * 4;  // 117,440,512

  k_zero<<<1, 32, 0, stream>>>(acc);

  // ---- mem argsort: pass0 keys on the fly; hist of passes 1-3 fused into
  // the preceding scatter; next-hist zeroing fused into scans ----
  {
    const int L = 256 * NC_MEM;
    k_radix_hist0<<<NB * NC_MEM, 256, 0, stream>>>(ml, gm, histA);
    k_radix_scan<<<NB, 1024, 0, stream>>>(histA, L, histB);
    k_radix_scatter0h<<<NB * NC_MEM, 256, 0, stream>>>(ml, gm, kvA, histA, histB, 40);
    k_radix_scan<<<NB, 1024, 0, stream>>>(histB, L, histA);
    k_radix_scatterh<<<NB * NC_MEM, 256, 0, stream>>>(kvA, kvB, histB, NMEM, NC_MEM, 40, histA, 48);
    k_radix_scan<<<NB, 1024, 0, stream>>>(histA, L, histB);
    k_radix_scatterh<<<NB * NC_MEM, 256, 0, stream>>>(kvB, kvA, histA, NMEM, NC_MEM, 48, histB, 56);
    k_radix_scan<<<NB, 1024, 0, stream>>>(histB, L, (unsigned*)0);
    k_radix_scatter_lo<<<NB * NC_MEM, 256, 0, stream>>>(kvA, perm, histB, NMEM, NC_MEM);
  }

  // mem PL logprob (row 3)
  {
    int nseg = NMEM / LSEG;  // 384
    kpl_seg <<<NB * (nseg / 4), 256, 0, stream>>>(ml, perm, NMEM, nseg, segM, segT, slog, acc, 3);
    kpl_scan<<<NB, 512, 0, stream>>>(segM, segT, nseg, sufM, sufT);
    kpl_main<<<NB * (nseg / 4), 256, 0, stream>>>(slog, NMEM, nseg, sufM, sufT, acc, 3);
  }

  // ---- conv1 + conv2 + pooling ----
  if (ws_size >= need_big) {
    k_conv1b<<<NB * NBLK_MEM, 256, 0, stream>>>(perm, pmw, pmb, mfbig);
    k_conv2b<<<NB * NBLK_MEM, 256, 0, stream>>>(mfbig, mcw, mcb, part, 0);
  } else {
    for (int g = 0; g < 2; g++) {
      k_conv1b<<<4 * NBLK_MEM, 256, 0, stream>>>(perm + (size_t)g * 4 * NMEM, pmw, pmb, mfsmall);
      k_conv2b<<<4 * NBLK_MEM, 256, 0, stream>>>(mfsmall, mcw, mcb, part, g * 4);
    }
  }
  k_pool_final<<<NB, 256, 0, stream>>>(part, pooled);

  // ---- op logits + keys ----
  k_oplogits<<<NOP / 256, 256, 0, stream>>>(pjw, pjb, pooled, gop, oplog, opkvA);

  // ---- op argsort (same fusion) ----
  {
    const int L = 256 * NC_OP;
    k_radix_hist<<<NB * NC_OP, 256, 0, stream>>>(opkvA, histA, NOP, NC_OP, 32);
    k_radix_scan<<<NB, 1024, 0, stream>>>(histA, L, histB);
    k_radix_scatterh<<<NB * NC_OP, 256, 0, stream>>>(opkvA, opkvB, histA, NOP, NC_OP, 32, histB, 40);
    k_radix_scan<<<NB, 1024, 0, stream>>>(histB, L, histA);
    k_radix_scatterh<<<NB * NC_OP, 256, 0, stream>>>(opkvB, opkvA, histB, NOP, NC_OP, 40, histA, 48);
    k_radix_scan<<<NB, 1024, 0, stream>>>(histA, L, histB);
    k_radix_scatterh<<<NB * NC_OP, 256, 0, stream>>>(opkvA, opkvB, histA, NOP, NC_OP, 48, histB, 56);
    k_radix_scan<<<NB, 1024, 0, stream>>>(histB, L, (unsigned*)0);
    k_radix_scatter_lo<<<NB * NC_OP, 256, 0, stream>>>(opkvB, oo, histB, NOP, NC_OP);
  }

  // op PL logprob (row 2)
  {
    int nseg = NOP / LSEG;   // 128
    kpl_seg <<<NB * (nseg / 4), 256, 0, stream>>>(oplog, oo, NOP, nseg, segM, segT, slog, acc, 2);
    kpl_scan<<<NB, 512, 0, stream>>>(segM, segT, nseg, sufM, sufT);
    kpl_main<<<NB * (nseg / 4), 256, 0, stream>>>(slog, NOP, nseg, sufM, sufT, acc, 2);
  }

  // penalties (rows 0,1)
  k_pen<<<NB * NOP / 256, 256, 0, stream>>>(perm, oo, acc);

  k_finalize<<<1, 32, 0, stream>>>(acc, out);
}

// Round 15
// 409.149 us; speedup vs baseline: 1.6819x; 1.6819x over previous
//
#include <hip/hip_runtime.h>
#include <math.h>

#define NB 8
#define NMEM 196608
#define NOP 65536
#define NBLK_MEM 768
#define LSEG 512
#define EPB 4096
#define NC_MEM 48   // NMEM / EPB
#define NC_OP 16    // NOP / EPB

static __device__ __forceinline__ unsigned keymap(float f) {
  unsigned u = __float_as_uint(f);
  return (u & 0x80000000u) ? ~u : (u | 0x80000000u);
}

// logsumexp state combiner: (M,T) represents M + log(T); T==0 is identity.
static __device__ __forceinline__ void comb(float& M1, float& T1, float M2, float T2) {
  if (T2 == 0.f) return;
  if (T1 == 0.f) { M1 = M2; T1 = T2; return; }
  float M = fmaxf(M1, M2);
  T1 = T1 * expf(M1 - M) + T2 * expf(M2 - M);
  M1 = M;
}

__global__ void k_zero(double* acc) {
  if (threadIdx.x < 32) acc[threadIdx.x] = 0.0;
}

// ---- radix sort: 4x8-bit passes, stable, 4096 elements/block ----
// Batch->XCD pinning: batch = blockIdx.x % 8 (per-batch working set stays in one L2).
// NOTE (R14 lesson): do NOT fuse next-pass histogram into scatter via global
// atomics — random-address device atomics tripled WRITE_SIZE and ran 4x slower
// than the separate LDS-aggregated histogram pass.
__global__ void k_radix_hist0(const float* __restrict__ ml, const float* __restrict__ gm,
                              unsigned* __restrict__ hist) {
  __shared__ unsigned h[256];
  int batch = blockIdx.x % NB, cb = blockIdx.x / NB;
  int t = threadIdx.x;
  h[t] = 0;
  __syncthreads();
  const float* pm = ml + (size_t)batch * NMEM + (size_t)cb * EPB;
  const float* pg = gm + (size_t)batch * NMEM + (size_t)cb * EPB;
  #pragma unroll
  for (int r = 0; r < 16; r++) {
    unsigned key = keymap(pm[r * 256 + t] + pg[r * 256 + t]);
    atomicAdd(&h[key & 255u], 1u);
  }
  __syncthreads();
  hist[((size_t)batch * 256 + t) * NC_MEM + cb] = h[t];
}

__global__ void k_radix_hist(const unsigned long long* __restrict__ src, unsigned* __restrict__ hist,
                             int nper, int nblk, int shift) {
  __shared__ unsigned h[256];
  int batch = blockIdx.x % NB, cb = blockIdx.x / NB;
  int t = threadIdx.x;
  h[t] = 0;
  __syncthreads();
  const unsigned long long* p = src + (size_t)batch * nper + (size_t)cb * EPB;
  #pragma unroll
  for (int r = 0; r < 16; r++) {
    unsigned long long v = p[r * 256 + t];
    unsigned d = (unsigned)(v >> shift) & 255u;
    atomicAdd(&h[d], 1u);
  }
  __syncthreads();
  hist[((size_t)batch * 256 + t) * nblk + cb] = h[t];
}

__global__ void __launch_bounds__(1024) k_radix_scan(unsigned* __restrict__ hist, int L) {
  int b = blockIdx.x, t = threadIdx.x;   // block b -> XCD b%8: hist L2-hot
  unsigned* h = hist + (size_t)b * L;
  int C = L / 1024;
  unsigned s = 0;
  for (int i = 0; i < C; i++) s += h[t * C + i];
  __shared__ unsigned ls[1024];
  ls[t] = s;
  __syncthreads();
  for (int off = 1; off < 1024; off <<= 1) {
    unsigned add = (t >= off) ? ls[t - off] : 0u;
    __syncthreads();
    ls[t] += add;
    __syncthreads();
  }
  unsigned run = (t > 0) ? ls[t - 1] : 0u;
  for (int i = 0; i < C; i++) { unsigned v = h[t * C + i]; h[t * C + i] = run; run += v; }
}

// stable in-block rank: pos = base[d] + run[d] + wave-exclusive + ballot lane rank.
#define SCATTER_BODY(GETV, WRITE)                                              \
  __shared__ unsigned base[256];                                               \
  __shared__ unsigned run[256];                                                \
  __shared__ unsigned wh[4][256];                                              \
  int t = threadIdx.x, lane = t & 63, wv = t >> 6;                             \
  base[t] = hist[((size_t)batch * 256 + t) * nblk + cb];                       \
  run[t] = 0;                                                                  \
  unsigned long long v[16];                                                    \
  GETV;                                                                        \
  __syncthreads();                                                             \
  _Pragma("unroll")                                                            \
  for (int r = 0; r < 16; r++) {                                               \
    unsigned d = (unsigned)(v[r] >> shift) & 255u;                             \
    unsigned long long m = ~0ull;                                              \
    _Pragma("unroll")                                                          \
    for (int bit = 0; bit < 8; bit++) {                                        \
      unsigned long long bal = __ballot((d >> bit) & 1u);                      \
      m &= ((d >> bit) & 1u) ? bal : ~bal;                                     \
    }                                                                          \
    unsigned rank = (unsigned)__popcll(m & ((1ull << lane) - 1ull));           \
    _Pragma("unroll")                                                          \
    for (int w = 0; w < 4; w++) wh[w][t] = 0;                                  \
    __syncthreads();                                                           \
    if (rank == 0) wh[wv][d] = (unsigned)__popcll(m);                          \
    __syncthreads();                                                           \
    {                                                                          \
      unsigned run_t = run[t];                                                 \
      _Pragma("unroll")                                                        \
      for (int w = 0; w < 4; w++) { unsigned x = wh[w][t]; wh[w][t] = run_t; run_t += x; } \
      run[t] = run_t;                                                          \
    }                                                                          \
    __syncthreads();                                                           \
    unsigned pos = base[d] + wh[wv][d] + rank;                                 \
    WRITE;                                                                     \
    __syncthreads();                                                           \
  }

__global__ void k_radix_scatter0(const float* __restrict__ ml, const float* __restrict__ gm,
                                 unsigned long long* __restrict__ dst, const unsigned* __restrict__ hist) {
  int batch = blockIdx.x % NB, cb = blockIdx.x / NB;
  const int nblk = NC_MEM, shift = 32;
  const float* pm = ml + (size_t)batch * NMEM + (size_t)cb * EPB;
  const float* pg = gm + (size_t)batch * NMEM + (size_t)cb * EPB;
  unsigned long long* q = dst + (size_t)batch * NMEM;
  SCATTER_BODY(
    { _Pragma("unroll")
      for (int r = 0; r < 16; r++) {
        unsigned key = keymap(pm[r * 256 + t] + pg[r * 256 + t]);
        v[r] = ((unsigned long long)key << 32) | (unsigned)(cb * EPB + r * 256 + t);
      } },
    { q[pos] = v[r]; })
}

__global__ void k_radix_scatter(const unsigned long long* __restrict__ src, unsigned long long* __restrict__ dst,
                                const unsigned* __restrict__ hist, int nper, int nblk, int shift) {
  int batch = blockIdx.x % NB, cb = blockIdx.x / NB;
  const unsigned long long* p = src + (size_t)batch * nper + (size_t)cb * EPB;
  unsigned long long* q = dst + (size_t)batch * nper;
  SCATTER_BODY(
    { _Pragma("unroll")
      for (int r = 0; r < 16; r++) v[r] = p[r * 256 + t]; },
    { q[pos] = v[r]; })
}

// last pass: write only the low 32 bits (the permutation index).
__global__ void k_radix_scatter_lo(const unsigned long long* __restrict__ src, unsigned* __restrict__ dst,
                                   const unsigned* __restrict__ hist, int nper, int nblk) {
  int batch = blockIdx.x % NB, cb = blockIdx.x / NB;
  const int shift = 56;
  const unsigned long long* p = src + (size_t)batch * nper + (size_t)cb * EPB;
  unsigned* q = dst + (size_t)batch * nper;
  SCATTER_BODY(
    { _Pragma("unroll")
      for (int r = 0; r < 16; r++) v[r] = p[r * 256 + t]; },
    { q[pos] = (unsigned)v[r]; })
}

// ---- Plackett-Luce: segmented reverse-cumlogsumexp ----
// Pass 1: one WAVE per segment; lane gathers 8 elements; shuffle butterfly reduce.
__global__ void kpl_seg(const float* __restrict__ logits, const unsigned* __restrict__ order,
                        int n, int nseg, float* __restrict__ segM, float* __restrict__ segT,
                        float* __restrict__ slog, double* __restrict__ acc, int row) {
  int b = blockIdx.x % NB;
  int sg = blockIdx.x / NB;
  int t = threadIdx.x, lane = t & 63, wv = t >> 6;
  int seg = sg * 4 + wv;
  const float* lg = logits + (size_t)b * n;
  const unsigned* od = order + (size_t)b * n + (size_t)seg * LSEG + lane * 8;
  uint4 i0 = *((const uint4*)od);
  uint4 i1 = *((const uint4*)(od + 4));
  float s0 = lg[i0.x], s1 = lg[i0.y], s2 = lg[i0.z], s3 = lg[i0.w];
  float s4 = lg[i1.x], s5 = lg[i1.y], s6 = lg[i1.z], s7 = lg[i1.w];
  float* sl = slog + (size_t)b * n + (size_t)seg * LSEG + lane * 8;
  *((float4*)sl) = make_float4(s0, s1, s2, s3);
  *((float4*)(sl + 4)) = make_float4(s4, s5, s6, s7);
  float m = fmaxf(fmaxf(fmaxf(s0, s1), fmaxf(s2, s3)),
                  fmaxf(fmaxf(s4, s5), fmaxf(s6, s7)));
  float T = expf(s0 - m) + expf(s1 - m) + expf(s2 - m) + expf(s3 - m)
          + expf(s4 - m) + expf(s5 - m) + expf(s6 - m) + expf(s7 - m);
  double ss = ((double)s0 + (double)s1) + ((double)s2 + (double)s3)
            + ((double)s4 + (double)s5) + ((double)s6 + (double)s7);
  #pragma unroll
  for (int off = 1; off < 64; off <<= 1) {
    float M2 = __shfl_xor(m, off);
    float T2 = __shfl_xor(T, off);
    comb(m, T, M2, T2);
    ss += __shfl_xor(ss, off);
  }
  __shared__ double sw[4];
  if (lane == 0) { segM[b * nseg + seg] = m; segT[b * nseg + seg] = T; sw[wv] = ss; }
  __syncthreads();
  if (t == 0) atomicAdd(&acc[row * 8 + b], (sw[0] + sw[1]) + (sw[2] + sw[3]));
}

__global__ void __launch_bounds__(512) kpl_scan(const float* __restrict__ segM, const float* __restrict__ segT,
                                                int nseg, float* __restrict__ sufM, float* __restrict__ sufT) {
  int b = blockIdx.x, t = threadIdx.x;
  __shared__ float sm[512], st_[512];
  float M = -INFINITY, T = 0.f;
  if (t < nseg) { M = segM[b * nseg + t]; T = segT[b * nseg + t]; }
  sm[t] = M; st_[t] = T;
  __syncthreads();
  for (int off = 1; off < 512; off <<= 1) {
    float M2 = -INFINITY, T2 = 0.f;
    if (t + off < 512) { M2 = sm[t + off]; T2 = st_[t + off]; }
    __syncthreads();
    comb(M, T, M2, T2);
    sm[t] = M; st_[t] = T;
    __syncthreads();
  }
  if (t < nseg) {
    float eM = -INFINITY, eT = 0.f;
    if (t + 1 < nseg) { eM = sm[t + 1]; eT = st_[t + 1]; }
    sufM[b * nseg + t] = eM; sufT[b * nseg + t] = eT;
  }
}

// Pass 3: one WAVE per segment; lane owns 8 slog elements; shfl suffix scan.
__global__ void kpl_main(const float* __restrict__ slog, int n, int nseg,
                         const float* __restrict__ sufM, const float* __restrict__ sufT,
                         double* __restrict__ acc, int row) {
  int b = blockIdx.x % NB;
  int sg = blockIdx.x / NB;
  int t = threadIdx.x, lane = t & 63, wv = t >> 6;
  int seg = sg * 4 + wv;
  const float* sl = slog + (size_t)b * n + (size_t)seg * LSEG + lane * 8;
  float4 a = *((const float4*)sl);
  float4 c = *((const float4*)(sl + 4));
  float s[8] = {a.x, a.y, a.z, a.w, c.x, c.y, c.z, c.w};
  float m = fmaxf(fmaxf(fmaxf(s[0], s[1]), fmaxf(s[2], s[3])),
                  fmaxf(fmaxf(s[4], s[5]), fmaxf(s[6], s[7])));
  float T = expf(s[0] - m) + expf(s[1] - m) + expf(s[2] - m) + expf(s[3] - m)
          + expf(s[4] - m) + expf(s[5] - m) + expf(s[6] - m) + expf(s[7] - m);
  #pragma unroll
  for (int off = 1; off < 64; off <<= 1) {
    float M2 = __shfl_down(m, off);
    float T2 = __shfl_down(T, off);
    if (lane + off < 64) comb(m, T, M2, T2);
  }
  float Mx = __shfl_down(m, 1);
  float Tx = __shfl_down(T, 1);
  if (lane == 63) { Mx = -INFINITY; Tx = 0.f; }
  comb(Mx, Tx, sufM[b * nseg + seg], sufT[b * nseg + seg]);
  float Ms[8], Ts[8];
  #pragma unroll
  for (int i = 7; i >= 0; i--) {
    float sv = s[i];
    if (Tx == 0.f) { Mx = sv; Tx = 1.f; }
    else if (sv > Mx) { Tx = Tx * expf(Mx - sv) + 1.f; Mx = sv; }
    else Tx += expf(sv - Mx);
    Ms[i] = Mx; Ts[i] = Tx;
  }
  double lsum = 0.0;
  #pragma unroll
  for (int i = 0; i < 8; i++) lsum += (double)Ms[i] + (double)logf(Ts[i]);
  #pragma unroll
  for (int off = 1; off < 64; off <<= 1) lsum += __shfl_xor(lsum, off);
  __shared__ double sw[4];
  if (lane == 0) sw[wv] = lsum;
  __syncthreads();
  if (t == 0) atomicAdd(&acc[row * 8 + b], -((sw[0] + sw[1]) + (sw[2] + sw[3])));
}

// conv1; mm block-uniform -> scalar weight loads.
__global__ void k_conv1b(const unsigned* __restrict__ permg, const float* __restrict__ pmw,
                         const float* __restrict__ pmb, float* __restrict__ mf) {
  int t = threadIdx.x;
  int b4 = blockIdx.x / NBLK_MEM;
  int g0 = (blockIdx.x % NBLK_MEM) * 256;
  int mm = g0 >> 16;
  int p = (g0 & 65535) + t;
  int i = p >> 8, j = p & 255;
  const unsigned* ad = permg + (size_t)b4 * NMEM + mm * 65536;
  float nb[3][3];
  #pragma unroll
  for (int di = 0; di < 3; di++)
    #pragma unroll
    for (int dj = 0; dj < 3; dj++) {
      int ii = i + di - 1, jj = j + dj - 1;
      nb[di][dj] = (ii >= 0 && ii < 256 && jj >= 0 && jj < 256) ? (float)ad[ii * 256 + jj] : 0.f;
    }
  unsigned c = ad[p];
  float o[8];
  #pragma unroll
  for (int oc = 0; oc < 8; oc++) {
    float s = pmb[mm * 8 + oc];
    #pragma unroll
    for (int di = 0; di < 3; di++)
      #pragma unroll
      for (int dj = 0; dj < 3; dj++)
        s += pmw[mm * 72 + oc * 9 + di * 3 + dj] * nb[di][dj];
    o[oc] = fmaxf(s, 0.f);
  }
  float4* dst = (float4*)(mf + ((size_t)b4 * NMEM + c) * 8);
  dst[0] = make_float4(o[0], o[1], o[2], o[3]);
  dst[1] = make_float4(o[4], o[5], o[6], o[7]);
}

// conv2: weights via scalar loads; pooled partials per block.
__global__ void k_conv2b(const float* __restrict__ mf, const float* __restrict__ mcw,
                         const float* __restrict__ mcb, double* __restrict__ part, int gb) {
  __shared__ float pw[4][16][4];
  int t = threadIdx.x;
  int b4 = blockIdx.x / NBLK_MEM;
  int blk = blockIdx.x % NBLK_MEM;
  int r = blk * 32 + (t >> 3);
  int l = t & 7;
  const float* base = mf + (size_t)b4 * (NMEM * 8);
  float nb[9][8];
  #pragma unroll
  for (int q = 0; q < 9; q++) {
    int rr = r + q / 3 - 1, ll = l + q % 3 - 1;
    if (rr >= 0 && rr < 24576 && ll >= 0 && ll < 8) {
      const float4* px = (const float4*)(base + ((size_t)rr * 8 + ll) * 8);
      float4 a = px[0], bb = px[1];
      nb[q][0] = a.x; nb[q][1] = a.y; nb[q][2] = a.z; nb[q][3] = a.w;
      nb[q][4] = bb.x; nb[q][5] = bb.y; nb[q][6] = bb.z; nb[q][7] = bb.w;
    } else {
      #pragma unroll
      for (int c = 0; c < 8; c++) nb[q][c] = 0.f;
    }
  }
  int lane = t & 63, wv = t >> 6;
  #pragma unroll
  for (int c2 = 0; c2 < 16; c2++) {
    float s = mcb[c2];
    #pragma unroll
    for (int c = 0; c < 8; c++)
      #pragma unroll
      for (int q = 0; q < 9; q++)
        s += mcw[c2 * 72 + c * 9 + q] * nb[q][c];
    float v = fmaxf(s, 0.f);
    v += __shfl_xor(v, 1);
    v += __shfl_xor(v, 8);
    v += __shfl_xor(v, 16);
    v += __shfl_xor(v, 32);
    if ((lane & 1) == 0 && ((t >> 3) & 7) == 0) pw[wv][c2][(lane & 7) >> 1] = v;
  }
  __syncthreads();
  if (t < 64) {
    int c2 = t >> 2, d = t & 3;
    double s = (double)pw[0][c2][d] + (double)pw[1][c2][d] + (double)pw[2][c2][d] + (double)pw[3][c2][d];
    part[((size_t)(gb + b4) * NBLK_MEM + blk) * 64 + t] = s;
  }
}

__global__ void k_pool_final(const double* __restrict__ part, double* __restrict__ pooled) {
  int b = blockIdx.x, t = threadIdx.x;
  int c2 = t >> 4, a = (t >> 2) & 3, d = t & 3;
  double s = 0.0;
  for (int j = 0; j < 192; j++)
    s += part[((size_t)b * NBLK_MEM + a * 192 + j) * 64 + c2 * 4 + d];
  pooled[b * 256 + t] = s / 12288.0;
}

__global__ void k_oplogits(const float* __restrict__ pjw, const float* __restrict__ pjb,
                           const double* __restrict__ pooled, const float* __restrict__ gop,
                           float* __restrict__ oplog, unsigned long long* __restrict__ opkv) {
  __shared__ double pl[8][256];
  int t = threadIdx.x;
  #pragma unroll
  for (int b = 0; b < 8; b++) pl[b][t] = pooled[b * 256 + t];
  __syncthreads();
  int k = blockIdx.x * 256 + t;
  const float4* row = (const float4*)(pjw + (size_t)k * 256);
  double acc[8];
  #pragma unroll
  for (int b = 0; b < 8; b++) acc[b] = 0.0;
  for (int j4 = 0; j4 < 64; j4++) {
    float4 w = row[j4];
    int j = j4 * 4;
    #pragma unroll
    for (int b = 0; b < 8; b++)
      acc[b] += (double)w.x * pl[b][j] + (double)w.y * pl[b][j + 1]
              + (double)w.z * pl[b][j + 2] + (double)w.w * pl[b][j + 3];
  }
  float bias = pjb[k];
  #pragma unroll
  for (int b = 0; b < 8; b++) {
    float ol = (float)(acc[b] + (double)bias);
    oplog[(size_t)b * NOP + k] = ol;
    float key = ol + gop[(size_t)b * NOP + k];
    opkv[(size_t)b * NOP + k] = ((unsigned long long)keymap(key) << 32) | (unsigned)k;
  }
}

static __device__ __forceinline__ float tierf(float h) {
  return h <= 2.f ? 1.f : (h <= 4.f ? 1.5f : (h <= 8.f ? 2.f : (h <= 16.f ? 3.f : 5.f)));
}
static __device__ __forceinline__ double penf(float d) {
  float fwd = d > 0.f ? d : 0.f;
  float bwd = d < 0.f ? -d : 0.f;
  return (double)(fwd * tierf(fwd)) + (double)(bwd * bwd * tierf(bwd));
}

__global__ void k_pen(const unsigned* __restrict__ perm, const unsigned* __restrict__ oo,
                      double* __restrict__ acc) {
  int b = blockIdx.x % NB;
  int k = (blockIdx.x / NB) * 256 + threadIdx.x;
  const unsigned* P = perm + (size_t)b * NMEM;
  float A = (float)P[k], Bv = (float)P[NOP + k], Cv = (float)P[2 * NOP + k];
  double pi = penf(Bv - A) + penf(Cv - Bv);
  double pe = 0.0;
  if (k < 65535) {
    unsigned k0 = oo[(size_t)b * NOP + k], k1 = oo[(size_t)b * NOP + k + 1];
    pe = penf((float)P[k1] - (float)P[2 * NOP + k0]);
  }
  __shared__ double ri[256], re[256];
  ri[threadIdx.x] = pi; re[threadIdx.x] = pe;
  __syncthreads();
  for (int off = 128; off > 0; off >>= 1) {
    if (threadIdx.x < off) { ri[threadIdx.x] += ri[threadIdx.x + off]; re[threadIdx.x] += re[threadIdx.x + off]; }
    __syncthreads();
  }
  if (threadIdx.x == 0) { atomicAdd(&acc[8 + b], ri[0]); atomicAdd(&acc[0 + b], re[0]); }
}

__global__ void k_finalize(const double* __restrict__ acc, float* __restrict__ out) {
  if (threadIdx.x < 32) out[threadIdx.x] = (float)acc[threadIdx.x];
}

extern "C" void kernel_launch(void* const* d_in, const int* in_sizes, int n_in,
                              void* d_out, int out_size, void* d_ws, size_t ws_size,
                              hipStream_t stream) {
  (void)in_sizes; (void)n_in; (void)out_size;
  const float* ml  = (const float*)d_in[0];
  const float* gm  = (const float*)d_in[1];
  const float* gop = (const float*)d_in[2];
  const float* pmw = (const float*)d_in[3];
  const float* pmb = (const float*)d_in[4];
  const float* mcw = (const float*)d_in[5];
  const float* mcb = (const float*)d_in[6];
  const float* pjw = (const float*)d_in[7];
  const float* pjb = (const float*)d_in[8];
  float* out = (float*)d_out;
  char* ws = (char*)d_ws;

  unsigned long long* kvA = (unsigned long long*)(ws + 0);          // 12,582,912
  unsigned long long* kvB = (unsigned long long*)(ws + 12582912);   // 12,582,912
  unsigned* hist   = (unsigned*)(ws + 25165824);                    //  <= 393,216
  unsigned* perm   = (unsigned*)(ws + 31457280);                    //  6,291,456
  double*   part   = (double*)(ws + 37748736);                      //  3,145,728
  double*   pooled = (double*)(ws + 40894464);
  double*   acc    = (double*)(ws + 40910848);
  float*    segM   = (float*)(ws + 40911104);
  float*    segT   = (float*)(ws + 40923392);
  float*    sufM   = (float*)(ws + 40935680);
  float*    sufT   = (float*)(ws + 40947968);
  float*    slog  = (float*)(ws + 12582912);                        // reuses dead kvB
  float* mfsmall = (float*)(ws + 0);                                // fallback conv region
  float* mfbig   = (float*)(ws + 67108864);                         // 8-batch conv region (50.3MB)
  unsigned long long* opkvA = (unsigned long long*)(ws + 0);
  unsigned long long* opkvB = (unsigned long long*)(ws + 4194304);
  float*    oplog = (float*)(ws + 8388608);
  unsigned* oo    = (unsigned*)(ws + 10485760);
  const size_t need_big = 67108864ull + (size_t)NB * NMEM * 8 * 4;  // 117,440,512

  k_zero<<<1, 32, 0, stream>>>(acc);

  // ---- mem argsort: pass0 builds keys on the fly; pass3 writes perm directly ----
  k_radix_hist0<<<NB * NC_MEM, 256, 0, stream>>>(ml, gm, hist);
  k_radix_scan<<<NB, 1024, 0, stream>>>(hist, 256 * NC_MEM);
  k_radix_scatter0<<<NB * NC_MEM, 256, 0, stream>>>(ml, gm, kvA, hist);
  k_radix_hist<<<NB * NC_MEM, 256, 0, stream>>>(kvA, hist, NMEM, NC_MEM, 40);
  k_radix_scan<<<NB, 1024, 0, stream>>>(hist, 256 * NC_MEM);
  k_radix_scatter<<<NB * NC_MEM, 256, 0, stream>>>(kvA, kvB, hist, NMEM, NC_MEM, 40);
  k_radix_hist<<<NB * NC_MEM, 256, 0, stream>>>(kvB, hist, NMEM, NC_MEM, 48);
  k_radix_scan<<<NB, 1024, 0, stream>>>(hist, 256 * NC_MEM);
  k_radix_scatter<<<NB * NC_MEM, 256, 0, stream>>>(kvB, kvA, hist, NMEM, NC_MEM, 48);
  k_radix_hist<<<NB * NC_MEM, 256, 0, stream>>>(kvA, hist, NMEM, NC_MEM, 56);
  k_radix_scan<<<NB, 1024, 0, stream>>>(hist, 256 * NC_MEM);
  k_radix_scatter_lo<<<NB * NC_MEM, 256, 0, stream>>>(kvA, perm, hist, NMEM, NC_MEM);

  // mem PL logprob (row 3)
  {
    int nseg = NMEM / LSEG;  // 384
    kpl_seg <<<NB * (nseg / 4), 256, 0, stream>>>(ml, perm, NMEM, nseg, segM, segT, slog, acc, 3);
    kpl_scan<<<NB, 512, 0, stream>>>(segM, segT, nseg, sufM, sufT);
    kpl_main<<<NB * (nseg / 4), 256, 0, stream>>>(slog, NMEM, nseg, sufM, sufT, acc, 3);
  }

  // ---- conv1 + conv2 + pooling (single launch over 8 batches when ws allows) ----
  if (ws_size >= need_big) {
    k_conv1b<<<NB * NBLK_MEM, 256, 0, stream>>>(perm, pmw, pmb, mfbig);
    k_conv2b<<<NB * NBLK_MEM, 256, 0, stream>>>(mfbig, mcw, mcb, part, 0);
  } else {
    for (int g = 0; g < 2; g++) {
      k_conv1b<<<4 * NBLK_MEM, 256, 0, stream>>>(perm + (size_t)g * 4 * NMEM, pmw, pmb, mfsmall);
      k_conv2b<<<4 * NBLK_MEM, 256, 0, stream>>>(mfsmall, mcw, mcb, part, g * 4);
    }
  }
  k_pool_final<<<NB, 256, 0, stream>>>(part, pooled);

  // ---- op logits + keys ----
  k_oplogits<<<NOP / 256, 256, 0, stream>>>(pjw, pjb, pooled, gop, oplog, opkvA);

  // ---- op argsort: pass3 writes oo directly ----
  k_radix_hist<<<NB * NC_OP, 256, 0, stream>>>(opkvA, hist, NOP, NC_OP, 32);
  k_radix_scan<<<NB, 1024, 0, stream>>>(hist, 256 * NC_OP);
  k_radix_scatter<<<NB * NC_OP, 256, 0, stream>>>(opkvA, opkvB, hist, NOP, NC_OP, 32);
  k_radix_hist<<<NB * NC_OP, 256, 0, stream>>>(opkvB, hist, NOP, NC_OP, 40);
  k_radix_scan<<<NB, 1024, 0, stream>>>(hist, 256 * NC_OP);
  k_radix_scatter<<<NB * NC_OP, 256, 0, stream>>>(opkvB, opkvA, hist, NOP, NC_OP, 40);
  k_radix_hist<<<NB * NC_OP, 256, 0, stream>>>(opkvA, hist, NOP, NC_OP, 48);
  k_radix_scan<<<NB, 1024, 0, stream>>>(hist, 256 * NC_OP);
  k_radix_scatter<<<NB * NC_OP, 256, 0, stream>>>(opkvA, opkvB, hist, NOP, NC_OP, 48);
  k_radix_hist<<<NB * NC_OP, 256, 0, stream>>>(opkvB, hist, NOP, NC_OP, 56);
  k_radix_scan<<<NB, 1024, 0, stream>>>(hist, 256 * NC_OP);
  k_radix_scatter_lo<<<NB * NC_OP, 256, 0, stream>>>(opkvB, oo, hist, NOP, NC_OP);

  // op PL logprob (row 2)
  {
    int nseg = NOP / LSEG;   // 128
    kpl_seg <<<NB * (nseg / 4), 256, 0, stream>>>(oplog, oo, NOP, nseg, segM, segT, slog, acc, 2);
    kpl_scan<<<NB, 512, 0, stream>>>(segM, segT, nseg, sufM, sufT);
    kpl_main<<<NB * (nseg / 4), 256, 0, stream>>>(slog, NOP, nseg, sufM, sufT, acc, 2);
  }

  // penalties (rows 0,1)
  k_pen<<<NB * NOP / 256, 256, 0, stream>>>(perm, oo, acc);

  k_finalize<<<1, 32, 0, stream>>>(acc, out);
}

// Round 16
// 395.265 us; speedup vs baseline: 1.7409x; 1.0351x over previous
//
#include <hip/hip_runtime.h>
#include <math.h>

#define NB 8
#define NMEM 196608
#define NOP 65536
#define NBLK_MEM 768
#define LSEG 512
#define EPB 4096
#define NC_MEM 48   // NMEM / EPB
#define NC_OP 16    // NOP / EPB

static __device__ __forceinline__ unsigned keymap(float f) {
  unsigned u = __float_as_uint(f);
  return (u & 0x80000000u) ? ~u : (u | 0x80000000u);
}

// logsumexp state combiner: (M,T) represents M + log(T); T==0 is identity.
static __device__ __forceinline__ void comb(float& M1, float& T1, float M2, float T2) {
  if (T2 == 0.f) return;
  if (T1 == 0.f) { M1 = M2; T1 = T2; return; }
  float M = fmaxf(M1, M2);
  T1 = T1 * expf(M1 - M) + T2 * expf(M2 - M);
  M1 = M;
}

__global__ void k_zero(double* acc) {
  if (threadIdx.x < 32) acc[threadIdx.x] = 0.0;
}

// ---- radix sort: 4x8-bit passes, stable, 4096 elements/block ----
// Batch->XCD pinning: batch = blockIdx.x % 8.
// R14 lesson: no global-atomic hist fusion. R16: scatter blocks are 1024
// threads / 4 rounds (16 barriers instead of 64) to unexpose barrier latency.
__global__ void k_radix_hist0(const float* __restrict__ ml, const float* __restrict__ gm,
                              unsigned* __restrict__ hist) {
  __shared__ unsigned h[256];
  int batch = blockIdx.x % NB, cb = blockIdx.x / NB;
  int t = threadIdx.x;
  h[t] = 0;
  __syncthreads();
  const float* pm = ml + (size_t)batch * NMEM + (size_t)cb * EPB;
  const float* pg = gm + (size_t)batch * NMEM + (size_t)cb * EPB;
  #pragma unroll
  for (int r = 0; r < 16; r++) {
    unsigned key = keymap(pm[r * 256 + t] + pg[r * 256 + t]);
    atomicAdd(&h[key & 255u], 1u);
  }
  __syncthreads();
  hist[((size_t)batch * 256 + t) * NC_MEM + cb] = h[t];
}

__global__ void k_radix_hist(const unsigned long long* __restrict__ src, unsigned* __restrict__ hist,
                             int nper, int nblk, int shift) {
  __shared__ unsigned h[256];
  int batch = blockIdx.x % NB, cb = blockIdx.x / NB;
  int t = threadIdx.x;
  h[t] = 0;
  __syncthreads();
  const unsigned long long* p = src + (size_t)batch * nper + (size_t)cb * EPB;
  #pragma unroll
  for (int r = 0; r < 16; r++) {
    unsigned long long v = p[r * 256 + t];
    unsigned d = (unsigned)(v >> shift) & 255u;
    atomicAdd(&h[d], 1u);
  }
  __syncthreads();
  hist[((size_t)batch * 256 + t) * nblk + cb] = h[t];
}

__global__ void __launch_bounds__(1024) k_radix_scan(unsigned* __restrict__ hist, int L) {
  int b = blockIdx.x, t = threadIdx.x;
  unsigned* h = hist + (size_t)b * L;
  int C = L / 1024;
  unsigned s = 0;
  for (int i = 0; i < C; i++) s += h[t * C + i];
  __shared__ unsigned ls[1024];
  ls[t] = s;
  __syncthreads();
  for (int off = 1; off < 1024; off <<= 1) {
    unsigned add = (t >= off) ? ls[t - off] : 0u;
    __syncthreads();
    ls[t] += add;
    __syncthreads();
  }
  unsigned run = (t > 0) ? ls[t - 1] : 0u;
  for (int i = 0; i < C; i++) { unsigned v = h[t * C + i]; h[t * C + i] = run; run += v; }
}

// stable scatter, 1024 threads / 4 rounds. Element order (round, wave, lane)
// matches memory order; fold walks 16 waves in order; run[] accumulates across
// rounds -> placement identical to the 256-thread version (bit-exact perm).
#define SCATTER_BODY(GETV, WRITE)                                              \
  __shared__ unsigned base[256];                                               \
  __shared__ unsigned run[256];                                                \
  __shared__ unsigned wh[16][256];                                             \
  int t = threadIdx.x, lane = t & 63, wv = t >> 6;                             \
  if (t < 256) { base[t] = hist[((size_t)batch * 256 + t) * nblk + cb]; run[t] = 0; } \
  unsigned long long v[4];                                                     \
  GETV;                                                                        \
  __syncthreads();                                                             \
  _Pragma("unroll")                                                            \
  for (int r = 0; r < 4; r++) {                                                \
    unsigned* whf = (unsigned*)wh;                                             \
    whf[t] = 0; whf[t + 1024] = 0; whf[t + 2048] = 0; whf[t + 3072] = 0;       \
    unsigned d = (unsigned)(v[r] >> shift) & 255u;                             \
    unsigned long long m = ~0ull;                                              \
    _Pragma("unroll")                                                          \
    for (int bit = 0; bit < 8; bit++) {                                        \
      unsigned long long bal = __ballot((d >> bit) & 1u);                      \
      m &= ((d >> bit) & 1u) ? bal : ~bal;                                     \
    }                                                                          \
    unsigned rank = (unsigned)__popcll(m & ((1ull << lane) - 1ull));           \
    __syncthreads();                                                           \
    if (rank == 0) wh[wv][d] = (unsigned)__popcll(m);                          \
    __syncthreads();                                                           \
    if (t < 256) {                                                             \
      unsigned run_t = run[t];                                                 \
      _Pragma("unroll")                                                        \
      for (int w = 0; w < 16; w++) { unsigned x = wh[w][t]; wh[w][t] = run_t; run_t += x; } \
      run[t] = run_t;                                                          \
    }                                                                          \
    __syncthreads();                                                           \
    unsigned pos = base[d] + wh[wv][d] + rank;                                 \
    WRITE;                                                                     \
    __syncthreads();                                                           \
  }

__global__ void __launch_bounds__(1024)
k_radix_scatter0(const float* __restrict__ ml, const float* __restrict__ gm,
                 unsigned long long* __restrict__ dst, const unsigned* __restrict__ hist) {
  int batch = blockIdx.x % NB, cb = blockIdx.x / NB;
  const int nblk = NC_MEM, shift = 32;
  const float* pm = ml + (size_t)batch * NMEM + (size_t)cb * EPB;
  const float* pg = gm + (size_t)batch * NMEM + (size_t)cb * EPB;
  unsigned long long* q = dst + (size_t)batch * NMEM;
  SCATTER_BODY(
    { _Pragma("unroll")
      for (int r = 0; r < 4; r++) {
        unsigned key = keymap(pm[r * 1024 + t] + pg[r * 1024 + t]);
        v[r] = ((unsigned long long)key << 32) | (unsigned)(cb * EPB + r * 1024 + t);
      } },
    { q[pos] = v[r]; })
}

__global__ void __launch_bounds__(1024)
k_radix_scatter(const unsigned long long* __restrict__ src, unsigned long long* __restrict__ dst,
                const unsigned* __restrict__ hist, int nper, int nblk, int shift) {
  int batch = blockIdx.x % NB, cb = blockIdx.x / NB;
  const unsigned long long* p = src + (size_t)batch * nper + (size_t)cb * EPB;
  unsigned long long* q = dst + (size_t)batch * nper;
  SCATTER_BODY(
    { _Pragma("unroll")
      for (int r = 0; r < 4; r++) v[r] = p[r * 1024 + t]; },
    { q[pos] = v[r]; })
}

// last pass: write only the low 32 bits (the permutation index).
__global__ void __launch_bounds__(1024)
k_radix_scatter_lo(const unsigned long long* __restrict__ src, unsigned* __restrict__ dst,
                   const unsigned* __restrict__ hist, int nper, int nblk) {
  int batch = blockIdx.x % NB, cb = blockIdx.x / NB;
  const int shift = 56;
  const unsigned long long* p = src + (size_t)batch * nper + (size_t)cb * EPB;
  unsigned* q = dst + (size_t)batch * nper;
  SCATTER_BODY(
    { _Pragma("unroll")
      for (int r = 0; r < 4; r++) v[r] = p[r * 1024 + t]; },
    { q[pos] = (unsigned)v[r]; })
}

// ---- Plackett-Luce: segmented reverse-cumlogsumexp ----
// Pass 1: one WAVE per segment; lane gathers 8 elements; shuffle butterfly reduce.
__global__ void kpl_seg(const float* __restrict__ logits, const unsigned* __restrict__ order,
                        int n, int nseg, float* __restrict__ segM, float* __restrict__ segT,
                        float* __restrict__ slog, double* __restrict__ acc, int row) {
  int b = blockIdx.x % NB;
  int sg = blockIdx.x / NB;
  int t = threadIdx.x, lane = t & 63, wv = t >> 6;
  int seg = sg * 4 + wv;
  const float* lg = logits + (size_t)b * n;
  const unsigned* od = order + (size_t)b * n + (size_t)seg * LSEG + lane * 8;
  uint4 i0 = *((const uint4*)od);
  uint4 i1 = *((const uint4*)(od + 4));
  float s0 = lg[i0.x], s1 = lg[i0.y], s2 = lg[i0.z], s3 = lg[i0.w];
  float s4 = lg[i1.x], s5 = lg[i1.y], s6 = lg[i1.z], s7 = lg[i1.w];
  float* sl = slog + (size_t)b * n + (size_t)seg * LSEG + lane * 8;
  *((float4*)sl) = make_float4(s0, s1, s2, s3);
  *((float4*)(sl + 4)) = make_float4(s4, s5, s6, s7);
  float m = fmaxf(fmaxf(fmaxf(s0, s1), fmaxf(s2, s3)),
                  fmaxf(fmaxf(s4, s5), fmaxf(s6, s7)));
  float T = expf(s0 - m) + expf(s1 - m) + expf(s2 - m) + expf(s3 - m)
          + expf(s4 - m) + expf(s5 - m) + expf(s6 - m) + expf(s7 - m);
  double ss = ((double)s0 + (double)s1) + ((double)s2 + (double)s3)
            + ((double)s4 + (double)s5) + ((double)s6 + (double)s7);
  #pragma unroll
  for (int off = 1; off < 64; off <<= 1) {
    float M2 = __shfl_xor(m, off);
    float T2 = __shfl_xor(T, off);
    comb(m, T, M2, T2);
    ss += __shfl_xor(ss, off);
  }
  __shared__ double sw[4];
  if (lane == 0) { segM[b * nseg + seg] = m; segT[b * nseg + seg] = T; sw[wv] = ss; }
  __syncthreads();
  if (t == 0) atomicAdd(&acc[row * 8 + b], (sw[0] + sw[1]) + (sw[2] + sw[3]));
}

__global__ void __launch_bounds__(512) kpl_scan(const float* __restrict__ segM, const float* __restrict__ segT,
                                                int nseg, float* __restrict__ sufM, float* __restrict__ sufT) {
  int b = blockIdx.x, t = threadIdx.x;
  __shared__ float sm[512], st_[512];
  float M = -INFINITY, T = 0.f;
  if (t < nseg) { M = segM[b * nseg + t]; T = segT[b * nseg + t]; }
  sm[t] = M; st_[t] = T;
  __syncthreads();
  for (int off = 1; off < 512; off <<= 1) {
    float M2 = -INFINITY, T2 = 0.f;
    if (t + off < 512) { M2 = sm[t + off]; T2 = st_[t + off]; }
    __syncthreads();
    comb(M, T, M2, T2);
    sm[t] = M; st_[t] = T;
    __syncthreads();
  }
  if (t < nseg) {
    float eM = -INFINITY, eT = 0.f;
    if (t + 1 < nseg) { eM = sm[t + 1]; eT = st_[t + 1]; }
    sufM[b * nseg + t] = eM; sufT[b * nseg + t] = eT;
  }
}

// Pass 3: one WAVE per segment; lane owns 8 slog elements; shfl suffix scan.
__global__ void kpl_main(const float* __restrict__ slog, int n, int nseg,
                         const float* __restrict__ sufM, const float* __restrict__ sufT,
                         double* __restrict__ acc, int row) {
  int b = blockIdx.x % NB;
  int sg = blockIdx.x / NB;
  int t = threadIdx.x, lane = t & 63, wv = t >> 6;
  int seg = sg * 4 + wv;
  const float* sl = slog + (size_t)b * n + (size_t)seg * LSEG + lane * 8;
  float4 a = *((const float4*)sl);
  float4 c = *((const float4*)(sl + 4));
  float s[8] = {a.x, a.y, a.z, a.w, c.x, c.y, c.z, c.w};
  float m = fmaxf(fmaxf(fmaxf(s[0], s[1]), fmaxf(s[2], s[3])),
                  fmaxf(fmaxf(s[4], s[5]), fmaxf(s[6], s[7])));
  float T = expf(s[0] - m) + expf(s[1] - m) + expf(s[2] - m) + expf(s[3] - m)
          + expf(s[4] - m) + expf(s[5] - m) + expf(s[6] - m) + expf(s[7] - m);
  #pragma unroll
  for (int off = 1; off < 64; off <<= 1) {
    float M2 = __shfl_down(m, off);
    float T2 = __shfl_down(T, off);
    if (lane + off < 64) comb(m, T, M2, T2);
  }
  float Mx = __shfl_down(m, 1);
  float Tx = __shfl_down(T, 1);
  if (lane == 63) { Mx = -INFINITY; Tx = 0.f; }
  comb(Mx, Tx, sufM[b * nseg + seg], sufT[b * nseg + seg]);
  float Ms[8], Ts[8];
  #pragma unroll
  for (int i = 7; i >= 0; i--) {
    float sv = s[i];
    if (Tx == 0.f) { Mx = sv; Tx = 1.f; }
    else if (sv > Mx) { Tx = Tx * expf(Mx - sv) + 1.f; Mx = sv; }
    else Tx += expf(sv - Mx);
    Ms[i] = Mx; Ts[i] = Tx;
  }
  double lsum = 0.0;
  #pragma unroll
  for (int i = 0; i < 8; i++) lsum += (double)Ms[i] + (double)logf(Ts[i]);
  #pragma unroll
  for (int off = 1; off < 64; off <<= 1) lsum += __shfl_xor(lsum, off);
  __shared__ double sw[4];
  if (lane == 0) sw[wv] = lsum;
  __syncthreads();
  if (t == 0) atomicAdd(&acc[row * 8 + b], -((sw[0] + sw[1]) + (sw[2] + sw[3])));
}

// conv1; mm block-uniform -> scalar weight loads.
__global__ void k_conv1b(const unsigned* __restrict__ permg, const float* __restrict__ pmw,
                         const float* __restrict__ pmb, float* __restrict__ mf) {
  int t = threadIdx.x;
  int b4 = blockIdx.x / NBLK_MEM;
  int g0 = (blockIdx.x % NBLK_MEM) * 256;
  int mm = g0 >> 16;
  int p = (g0 & 65535) + t;
  int i = p >> 8, j = p & 255;
  const unsigned* ad = permg + (size_t)b4 * NMEM + mm * 65536;
  float nb[3][3];
  #pragma unroll
  for (int di = 0; di < 3; di++)
    #pragma unroll
    for (int dj = 0; dj < 3; dj++) {
      int ii = i + di - 1, jj = j + dj - 1;
      nb[di][dj] = (ii >= 0 && ii < 256 && jj >= 0 && jj < 256) ? (float)ad[ii * 256 + jj] : 0.f;
    }
  unsigned c = ad[p];
  float o[8];
  #pragma unroll
  for (int oc = 0; oc < 8; oc++) {
    float s = pmb[mm * 8 + oc];
    #pragma unroll
    for (int di = 0; di < 3; di++)
      #pragma unroll
      for (int dj = 0; dj < 3; dj++)
        s += pmw[mm * 72 + oc * 9 + di * 3 + dj] * nb[di][dj];
    o[oc] = fmaxf(s, 0.f);
  }
  float4* dst = (float4*)(mf + ((size_t)b4 * NMEM + c) * 8);
  dst[0] = make_float4(o[0], o[1], o[2], o[3]);
  dst[1] = make_float4(o[4], o[5], o[6], o[7]);
}

// conv2: weights via scalar loads; pooled partials per block.
__global__ void k_conv2b(const float* __restrict__ mf, const float* __restrict__ mcw,
                         const float* __restrict__ mcb, double* __restrict__ part, int gb) {
  __shared__ float pw[4][16][4];
  int t = threadIdx.x;
  int b4 = blockIdx.x / NBLK_MEM;
  int blk = blockIdx.x % NBLK_MEM;
  int r = blk * 32 + (t >> 3);
  int l = t & 7;
  const float* base = mf + (size_t)b4 * (NMEM * 8);
  float nb[9][8];
  #pragma unroll
  for (int q = 0; q < 9; q++) {
    int rr = r + q / 3 - 1, ll = l + q % 3 - 1;
    if (rr >= 0 && rr < 24576 && ll >= 0 && ll < 8) {
      const float4* px = (const float4*)(base + ((size_t)rr * 8 + ll) * 8);
      float4 a = px[0], bb = px[1];
      nb[q][0] = a.x; nb[q][1] = a.y; nb[q][2] = a.z; nb[q][3] = a.w;
      nb[q][4] = bb.x; nb[q][5] = bb.y; nb[q][6] = bb.z; nb[q][7] = bb.w;
    } else {
      #pragma unroll
      for (int c = 0; c < 8; c++) nb[q][c] = 0.f;
    }
  }
  int lane = t & 63, wv = t >> 6;
  #pragma unroll
  for (int c2 = 0; c2 < 16; c2++) {
    float s = mcb[c2];
    #pragma unroll
    for (int c = 0; c < 8; c++)
      #pragma unroll
      for (int q = 0; q < 9; q++)
        s += mcw[c2 * 72 + c * 9 + q] * nb[q][c];
    float v = fmaxf(s, 0.f);
    v += __shfl_xor(v, 1);
    v += __shfl_xor(v, 8);
    v += __shfl_xor(v, 16);
    v += __shfl_xor(v, 32);
    if ((lane & 1) == 0 && ((t >> 3) & 7) == 0) pw[wv][c2][(lane & 7) >> 1] = v;
  }
  __syncthreads();
  if (t < 64) {
    int c2 = t >> 2, d = t & 3;
    double s = (double)pw[0][c2][d] + (double)pw[1][c2][d] + (double)pw[2][c2][d] + (double)pw[3][c2][d];
    part[((size_t)(gb + b4) * NBLK_MEM + blk) * 64 + t] = s;
  }
}

__global__ void k_pool_final(const double* __restrict__ part, double* __restrict__ pooled) {
  int b = blockIdx.x, t = threadIdx.x;
  int c2 = t >> 4, a = (t >> 2) & 3, d = t & 3;
  double s = 0.0;
  for (int j = 0; j < 192; j++)
    s += part[((size_t)b * NBLK_MEM + a * 192 + j) * 64 + c2 * 4 + d];
  pooled[b * 256 + t] = s / 12288.0;
}

__global__ void k_oplogits(const float* __restrict__ pjw, const float* __restrict__ pjb,
                           const double* __restrict__ pooled, const float* __restrict__ gop,
                           float* __restrict__ oplog, unsigned long long* __restrict__ opkv) {
  __shared__ double pl[8][256];
  int t = threadIdx.x;
  #pragma unroll
  for (int b = 0; b < 8; b++) pl[b][t] = pooled[b * 256 + t];
  __syncthreads();
  int k = blockIdx.x * 256 + t;
  const float4* row = (const float4*)(pjw + (size_t)k * 256);
  double acc[8];
  #pragma unroll
  for (int b = 0; b < 8; b++) acc[b] = 0.0;
  for (int j4 = 0; j4 < 64; j4++) {
    float4 w = row[j4];
    int j = j4 * 4;
    #pragma unroll
    for (int b = 0; b < 8; b++)
      acc[b] += (double)w.x * pl[b][j] + (double)w.y * pl[b][j + 1]
              + (double)w.z * pl[b][j + 2] + (double)w.w * pl[b][j + 3];
  }
  float bias = pjb[k];
  #pragma unroll
  for (int b = 0; b < 8; b++) {
    float ol = (float)(acc[b] + (double)bias);
    oplog[(size_t)b * NOP + k] = ol;
    float key = ol + gop[(size_t)b * NOP + k];
    opkv[(size_t)b * NOP + k] = ((unsigned long long)keymap(key) << 32) | (unsigned)k;
  }
}

static __device__ __forceinline__ float tierf(float h) {
  return h <= 2.f ? 1.f : (h <= 4.f ? 1.5f : (h <= 8.f ? 2.f : (h <= 16.f ? 3.f : 5.f)));
}
static __device__ __forceinline__ double penf(float d) {
  float fwd = d > 0.f ? d : 0.f;
  float bwd = d < 0.f ? -d : 0.f;
  return (double)(fwd * tierf(fwd)) + (double)(bwd * bwd * tierf(bwd));
}

__global__ void k_pen(const unsigned* __restrict__ perm, const unsigned* __restrict__ oo,
                      double* __restrict__ acc) {
  int b = blockIdx.x % NB;
  int k = (blockIdx.x / NB) * 256 + threadIdx.x;
  const unsigned* P = perm + (size_t)b * NMEM;
  float A = (float)P[k], Bv = (float)P[NOP + k], Cv = (float)P[2 * NOP + k];
  double pi = penf(Bv - A) + penf(Cv - Bv);
  double pe = 0.0;
  if (k < 65535) {
    unsigned k0 = oo[(size_t)b * NOP + k], k1 = oo[(size_t)b * NOP + k + 1];
    pe = penf((float)P[k1] - (float)P[2 * NOP + k0]);
  }
  __shared__ double ri[256], re[256];
  ri[threadIdx.x] = pi; re[threadIdx.x] = pe;
  __syncthreads();
  for (int off = 128; off > 0; off >>= 1) {
    if (threadIdx.x < off) { ri[threadIdx.x] += ri[threadIdx.x + off]; re[threadIdx.x] += re[threadIdx.x + off]; }
    __syncthreads();
  }
  if (threadIdx.x == 0) { atomicAdd(&acc[8 + b], ri[0]); atomicAdd(&acc[0 + b], re[0]); }
}

__global__ void k_finalize(const double* __restrict__ acc, float* __restrict__ out) {
  if (threadIdx.x < 32) out[threadIdx.x] = (float)acc[threadIdx.x];
}

extern "C" void kernel_launch(void* const* d_in, const int* in_sizes, int n_in,
                              void* d_out, int out_size, void* d_ws, size_t ws_size,
                              hipStream_t stream) {
  (void)in_sizes; (void)n_in; (void)out_size;
  const float* ml  = (const float*)d_in[0];
  const float* gm  = (const float*)d_in[1];
  const float* gop = (const float*)d_in[2];
  const float* pmw = (const float*)d_in[3];
  const float* pmb = (const float*)d_in[4];
  const float* mcw = (const float*)d_in[5];
  const float* mcb = (const float*)d_in[6];
  const float* pjw = (const float*)d_in[7];
  const float* pjb = (const float*)d_in[8];
  float* out = (float*)d_out;
  char* ws = (char*)d_ws;

  unsigned long long* kvA = (unsigned long long*)(ws + 0);          // 12,582,912
  unsigned long long* kvB = (unsigned long long*)(ws + 12582912);   // 12,582,912
  unsigned* hist   = (unsigned*)(ws + 25165824);                    //  <= 393,216
  unsigned* perm   = (unsigned*)(ws + 31457280);                    //  6,291,456
  double*   part   = (double*)(ws + 37748736);                      //  3,145,728
  double*   pooled = (double*)(ws + 40894464);
  double*   acc    = (double*)(ws + 40910848);
  float*    segM   = (float*)(ws + 40911104);
  float*    segT   = (float*)(ws + 40923392);
  float*    sufM   = (float*)(ws + 40935680);
  float*    sufT   = (float*)(ws + 40947968);
  float*    slog  = (float*)(ws + 12582912);                        // reuses dead kvB
  float* mfsmall = (float*)(ws + 0);                                // fallback conv region
  float* mfbig   = (float*)(ws + 67108864);                         // 8-batch conv region (50.3MB)
  unsigned long long* opkvA = (unsigned long long*)(ws + 0);
  unsigned long long* opkvB = (unsigned long long*)(ws + 4194304);
  float*    oplog = (float*)(ws + 8388608);
  unsigned* oo    = (unsigned*)(ws + 10485760);
  const size_t need_big = 67108864ull + (size_t)NB * NMEM * 8 * 4;  // 117,440,512

  k_zero<<<1, 32, 0, stream>>>(acc);

  // ---- mem argsort: pass0 builds keys on the fly; pass3 writes perm directly ----
  k_radix_hist0<<<NB * NC_MEM, 256, 0, stream>>>(ml, gm, hist);
  k_radix_scan<<<NB, 1024, 0, stream>>>(hist, 256 * NC_MEM);
  k_radix_scatter0<<<NB * NC_MEM, 1024, 0, stream>>>(ml, gm, kvA, hist);
  k_radix_hist<<<NB * NC_MEM, 256, 0, stream>>>(kvA, hist, NMEM, NC_MEM, 40);
  k_radix_scan<<<NB, 1024, 0, stream>>>(hist, 256 * NC_MEM);
  k_radix_scatter<<<NB * NC_MEM, 1024, 0, stream>>>(kvA, kvB, hist, NMEM, NC_MEM, 40);
  k_radix_hist<<<NB * NC_MEM, 256, 0, stream>>>(kvB, hist, NMEM, NC_MEM, 48);
  k_radix_scan<<<NB, 1024, 0, stream>>>(hist, 256 * NC_MEM);
  k_radix_scatter<<<NB * NC_MEM, 1024, 0, stream>>>(kvB, kvA, hist, NMEM, NC_MEM, 48);
  k_radix_hist<<<NB * NC_MEM, 256, 0, stream>>>(kvA, hist, NMEM, NC_MEM, 56);
  k_radix_scan<<<NB, 1024, 0, stream>>>(hist, 256 * NC_MEM);
  k_radix_scatter_lo<<<NB * NC_MEM, 1024, 0, stream>>>(kvA, perm, hist, NMEM, NC_MEM);

  // mem PL logprob (row 3)
  {
    int nseg = NMEM / LSEG;  // 384
    kpl_seg <<<NB * (nseg / 4), 256, 0, stream>>>(ml, perm, NMEM, nseg, segM, segT, slog, acc, 3);
    kpl_scan<<<NB, 512, 0, stream>>>(segM, segT, nseg, sufM, sufT);
    kpl_main<<<NB * (nseg / 4), 256, 0, stream>>>(slog, NMEM, nseg, sufM, sufT, acc, 3);
  }

  // ---- conv1 + conv2 + pooling (single launch over 8 batches when ws allows) ----
  if (ws_size >= need_big) {
    k_conv1b<<<NB * NBLK_MEM, 256, 0, stream>>>(perm, pmw, pmb, mfbig);
    k_conv2b<<<NB * NBLK_MEM, 256, 0, stream>>>(mfbig, mcw, mcb, part, 0);
  } else {
    for (int g = 0; g < 2; g++) {
      k_conv1b<<<4 * NBLK_MEM, 256, 0, stream>>>(perm + (size_t)g * 4 * NMEM, pmw, pmb, mfsmall);
      k_conv2b<<<4 * NBLK_MEM, 256, 0, stream>>>(mfsmall, mcw, mcb, part, g * 4);
    }
  }
  k_pool_final<<<NB, 256, 0, stream>>>(part, pooled);

  // ---- op logits + keys ----
  k_oplogits<<<NOP / 256, 256, 0, stream>>>(pjw, pjb, pooled, gop, oplog, opkvA);

  // ---- op argsort: pass3 writes oo directly ----
  k_radix_hist<<<NB * NC_OP, 256, 0, stream>>>(opkvA, hist, NOP, NC_OP, 32);
  k_radix_scan<<<NB, 1024, 0, stream>>>(hist, 256 * NC_OP);
  k_radix_scatter<<<NB * NC_OP, 1024, 0, stream>>>(opkvA, opkvB, hist, NOP, NC_OP, 32);
  k_radix_hist<<<NB * NC_OP, 256, 0, stream>>>(opkvB, hist, NOP, NC_OP, 40);
  k_radix_scan<<<NB, 1024, 0, stream>>>(hist, 256 * NC_OP);
  k_radix_scatter<<<NB * NC_OP, 1024, 0, stream>>>(opkvB, opkvA, hist, NOP, NC_OP, 40);
  k_radix_hist<<<NB * NC_OP, 256, 0, stream>>>(opkvA, hist, NOP, NC_OP, 48);
  k_radix_scan<<<NB, 1024, 0, stream>>>(hist, 256 * NC_OP);
  k_radix_scatter<<<NB * NC_OP, 1024, 0, stream>>>(opkvA, opkvB, hist, NOP, NC_OP, 48);
  k_radix_hist<<<NB * NC_OP, 256, 0, stream>>>(opkvB, hist, NOP, NC_OP, 56);
  k_radix_scan<<<NB, 1024, 0, stream>>>(hist, 256 * NC_OP);
  k_radix_scatter_lo<<<NB * NC_OP, 1024, 0, stream>>>(opkvB, oo, hist, NOP, NC_OP);

  // op PL logprob (row 2)
  {
    int nseg = NOP / LSEG;   // 128
    kpl_seg <<<NB * (nseg / 4), 256, 0, stream>>>(oplog, oo, NOP, nseg, segM, segT, slog, acc, 2);
    kpl_scan<<<NB, 512, 0, stream>>>(segM, segT, nseg, sufM, sufT);
    kpl_main<<<NB * (nseg / 4), 256, 0, stream>>>(slog, NOP, nseg, sufM, sufT, acc, 2);
  }

  // penalties (rows 0,1)
  k_pen<<<NB * NOP / 256, 256, 0, stream>>>(perm, oo, acc);

  k_finalize<<<1, 32, 0, stream>>>(acc, out);
}